// Round 2
// baseline (293.125 us; speedup 1.0000x reference)
//
#include <hip/hip_runtime.h>
#include <math.h>

#define B_  8
#define N_  2048
#define F_  128
#define H1_ 32
#define H2_ 64
#define D1_ 128

// ---------------- kernel 1: xw1 = x @ W1   [B*N,128] @ [128,32] ----------------
__global__ __launch_bounds__(256) void k_xw1(const float* __restrict__ x,
                                             const float* __restrict__ W1,
                                             float* __restrict__ xw1) {
  __shared__ float w_s[F_ * H1_];
  for (int i = threadIdx.x; i < F_ * H1_; i += 256) w_s[i] = W1[i];
  __syncthreads();
  int idx = blockIdx.x * 256 + threadIdx.x;     // over B*N*H1
  int row = idx >> 5, col = idx & 31;
  const float* xr = x + (size_t)row * F_;
  float acc = 0.f;
#pragma unroll
  for (int k = 0; k < F_; k += 4) {
    float4 xv = *(const float4*)(xr + k);
    acc = fmaf(xv.x, w_s[(k + 0) * H1_ + col], acc);
    acc = fmaf(xv.y, w_s[(k + 1) * H1_ + col], acc);
    acc = fmaf(xv.z, w_s[(k + 2) * H1_ + col], acc);
    acc = fmaf(xv.w, w_s[(k + 3) * H1_ + col], acc);
  }
  xw1[idx] = acc;
}

// ---------------- kernel 3: hw2 = h1 @ W2   [B*N,32] @ [32,64] ----------------
__global__ __launch_bounds__(256) void k_hw2(const float* __restrict__ h1,
                                             const float* __restrict__ W2,
                                             float* __restrict__ hw2) {
  __shared__ float w_s[H1_ * H2_];
  for (int i = threadIdx.x; i < H1_ * H2_; i += 256) w_s[i] = W2[i];
  __syncthreads();
  int idx = blockIdx.x * 256 + threadIdx.x;     // over B*N*H2
  int row = idx >> 6, col = idx & 63;
  const float* hr = h1 + (size_t)row * H1_;
  float acc = 0.f;
#pragma unroll
  for (int k = 0; k < H1_; k += 4) {
    float4 hv = *(const float4*)(hr + k);
    acc = fmaf(hv.x, w_s[(k + 0) * H2_ + col], acc);
    acc = fmaf(hv.y, w_s[(k + 1) * H2_ + col], acc);
    acc = fmaf(hv.z, w_s[(k + 2) * H2_ + col], acc);
    acc = fmaf(hv.w, w_s[(k + 3) * H2_ + col], acc);
  }
  hw2[idx] = acc;
}

// -------- kernels 2/4: Out = relu(A @ B + bias), per batch A=[2048,2048] --------
// BM=64 rows/block, BK=32 K-chunk, 256 threads: 16 col-groups x 16 row-groups,
// each thread 4 rows x CPT cols. A staged transposed in LDS (+4 pad -> aligned
// conflict-free float4 reads); next A-tile prefetched into registers so HBM
// latency hides under the 32-k FMA chunk. B (small, L2-resident) read from
// global with same-address broadcast.
template<int H, int CPT>
__global__ __launch_bounds__(256) void k_agemm_relu(const float* __restrict__ A,
                                                    const float* __restrict__ Bm,
                                                    const float* __restrict__ bias,
                                                    float* __restrict__ Out) {
  constexpr int BM = 64, BK = 32;
  constexpr int CG = H / CPT;               // 16
  constexpr int RG = 256 / CG;              // 16
  constexpr int RPT = BM / RG;              // 4
  constexpr int QPT = (BM * BK / 4) / 256;  // 2 float4 loads per thread per chunk
  __shared__ float a_s[BK][BM + 4];

  const int batch = blockIdx.y;
  const int m0 = blockIdx.x * BM;
  const float* Ab = A + (size_t)batch * N_ * N_ + (size_t)m0 * N_;
  const float* Bb = Bm + (size_t)batch * N_ * H;
  const int tx = threadIdx.x % CG;
  const int ty = threadIdx.x / CG;
  const int r0 = ty * RPT;
  const int c0 = tx * CPT;

  int qrow[QPT], qk[QPT];
#pragma unroll
  for (int i = 0; i < QPT; ++i) {
    int q = threadIdx.x + i * 256;
    qrow[i] = q >> 3;            // 8 quads per row (BK/4)
    qk[i] = (q & 7) * 4;
  }
  float4 pref[QPT];
#pragma unroll
  for (int i = 0; i < QPT; ++i)
    pref[i] = *(const float4*)(Ab + (size_t)qrow[i] * N_ + qk[i]);

  float acc[RPT][CPT] = {};

  for (int kk = 0; kk < N_; kk += BK) {
    if (kk) __syncthreads();            // everyone done reading previous tile
#pragma unroll
    for (int i = 0; i < QPT; ++i) {     // transposed store
      a_s[qk[i] + 0][qrow[i]] = pref[i].x;
      a_s[qk[i] + 1][qrow[i]] = pref[i].y;
      a_s[qk[i] + 2][qrow[i]] = pref[i].z;
      a_s[qk[i] + 3][qrow[i]] = pref[i].w;
    }
    __syncthreads();
    if (kk + BK < N_) {                 // prefetch next tile (hidden by compute)
#pragma unroll
      for (int i = 0; i < QPT; ++i)
        pref[i] = *(const float4*)(Ab + (size_t)qrow[i] * N_ + (kk + BK) + qk[i]);
    }
    const float* Bk = Bb + (size_t)kk * H + c0;
#pragma unroll
    for (int k = 0; k < BK; ++k) {
      float av[RPT];
      *(float4*)av = *(const float4*)&a_s[k][r0];     // aligned: (68k+16*ty)*4B
      float bv[CPT];
      if constexpr (CPT == 4) *(float4*)bv = *(const float4*)(Bk + k * H);
      else                    *(float2*)bv = *(const float2*)(Bk + k * H);
#pragma unroll
      for (int r = 0; r < RPT; ++r)
#pragma unroll
        for (int c = 0; c < CPT; ++c)
          acc[r][c] = fmaf(av[r], bv[c], acc[r][c]);
    }
  }
#pragma unroll
  for (int r = 0; r < RPT; ++r) {
    size_t o = ((size_t)batch * N_ + (m0 + r0 + r)) * H + c0;
#pragma unroll
    for (int c = 0; c < CPT; ++c)
      Out[o + c] = fmaxf(acc[r][c] + bias[c0 + c], 0.f);
  }
}

// -------- kernel 5a: K-split partials of flat(h2) @ Wd ; Wd streamed once --------
__global__ __launch_bounds__(256) void k_dense_part(const float* __restrict__ h2,
                                                    const float* __restrict__ Wd,
                                                    float* __restrict__ part) {
  constexpr int KC = 512;                  // K rows per block; grid = 131072/512 = 256
  __shared__ float hs[B_][KC];
  const int kc0 = blockIdx.x * KC;
#pragma unroll
  for (int i = 0; i < 4; ++i) {            // stage 8 x 512 floats, coalesced
    int q = threadIdx.x + i * 256;
    int b = q >> 7;
    int kq = (q & 127) * 4;
    *(float4*)&hs[b][kq] = *(const float4*)(h2 + (size_t)b * (N_ * H2_) + kc0 + kq);
  }
  __syncthreads();
  const int d0 = (threadIdx.x & 31) * 4;   // 4 output cols per thread
  const int b  = threadIdx.x >> 5;         // 1 batch per thread
  float a0 = 0.f, a1 = 0.f, a2 = 0.f, a3 = 0.f;
  const float* wp = Wd + (size_t)kc0 * D1_ + d0;
#pragma unroll 4
  for (int k = 0; k < KC; ++k) {
    float4 w = *(const float4*)(wp + (size_t)k * D1_);
    float h = hs[b][k];
    a0 = fmaf(h, w.x, a0);
    a1 = fmaf(h, w.y, a1);
    a2 = fmaf(h, w.z, a2);
    a3 = fmaf(h, w.w, a3);
  }
  float* pp = part + ((size_t)blockIdx.x * B_ + b) * D1_ + d0;
  *(float4*)pp = make_float4(a0, a1, a2, a3);
}

// -------- kernel 5b: reduce partials + bias + relu -> hd [8,128] --------
__global__ __launch_bounds__(256) void k_dense_reduce(const float* __restrict__ part,
                                                      const float* __restrict__ bd,
                                                      float* __restrict__ hd) {
  int idx = blockIdx.x * 256 + threadIdx.x;   // 0..1023 = b*128+d
  float s = 0.f;
  for (int i = 0; i < 256; ++i) s += part[(size_t)i * (B_ * D1_) + idx];
  hd[idx] = fmaxf(s + bd[idx & (D1_ - 1)], 0.f);
}

// -------- kernel 6: out[b] = sigmoid(hd[b,:] . Wo + bo) --------
__global__ __launch_bounds__(512) void k_final(const float* __restrict__ hd,
                                               const float* __restrict__ Wo,
                                               const float* __restrict__ bo,
                                               float* __restrict__ out) {
  int w = threadIdx.x >> 6;   // wave id = batch
  int l = threadIdx.x & 63;
  float v = hd[w * D1_ + l] * Wo[l] + hd[w * D1_ + 64 + l] * Wo[64 + l];
#pragma unroll
  for (int off = 32; off; off >>= 1) v += __shfl_down(v, off, 64);
  if (l == 0) out[w] = 1.f / (1.f + expf(-(v + bo[0])));
}

extern "C" void kernel_launch(void* const* d_in, const int* in_sizes, int n_in,
                              void* d_out, int out_size, void* d_ws, size_t ws_size,
                              hipStream_t stream) {
  const float* x  = (const float*)d_in[0];
  const float* a  = (const float*)d_in[1];
  const float* W1 = (const float*)d_in[2];
  const float* b1 = (const float*)d_in[3];
  const float* W2 = (const float*)d_in[4];
  const float* b2 = (const float*)d_in[5];
  const float* Wd = (const float*)d_in[6];
  const float* bd = (const float*)d_in[7];
  const float* Wo = (const float*)d_in[8];
  const float* bo = (const float*)d_in[9];
  float* out = (float*)d_out;

  // workspace layout (floats): total 3,408,896 floats = 13.6 MB
  float* ws   = (float*)d_ws;
  float* xw1  = ws;                       // 8*2048*32  = 524288
  float* h1   = xw1 + 524288;             // 524288
  float* hw2  = h1 + 524288;              // 8*2048*64  = 1048576
  float* h2   = hw2 + 1048576;            // 1048576
  float* part = h2 + 1048576;             // 256*8*128  = 262144
  float* hd   = part + 262144;            // 1024

  k_xw1<<<(B_ * N_ * H1_) / 256, 256, 0, stream>>>(x, W1, xw1);
  k_agemm_relu<H1_, 2><<<dim3(N_ / 64, B_), 256, 0, stream>>>(a, xw1, b1, h1);
  k_hw2<<<(B_ * N_ * H2_) / 256, 256, 0, stream>>>(h1, W2, hw2);
  k_agemm_relu<H2_, 4><<<dim3(N_ / 64, B_), 256, 0, stream>>>(a, hw2, b2, h2);
  k_dense_part<<<(N_ * H2_) / 512, 256, 0, stream>>>(h2, Wd, part);
  k_dense_reduce<<<4, 256, 0, stream>>>(part, bd, hd);
  k_final<<<1, 512, 0, stream>>>(hd, Wo, bo, out);
}

// Round 3
// 276.127 us; speedup vs baseline: 1.0616x; 1.0616x over previous
//
#include <hip/hip_runtime.h>
#include <math.h>

#define B_  8
#define N_  2048
#define F_  128
#define H1_ 32
#define H2_ 64
#define D1_ 128
#define KS_ 4            // K-split factor for the A-GEMMs
#define KSEG_ (N_ / KS_) // 512 K per block

// ---------------- kernel 1: xw1 = x @ W1   [B*N,128] @ [128,32] ----------------
__global__ __launch_bounds__(256) void k_xw1(const float* __restrict__ x,
                                             const float* __restrict__ W1,
                                             float* __restrict__ xw1) {
  __shared__ float w_s[F_ * H1_];
  for (int i = threadIdx.x; i < F_ * H1_; i += 256) w_s[i] = W1[i];
  __syncthreads();
  int idx = blockIdx.x * 256 + threadIdx.x;     // over B*N*H1
  int row = idx >> 5, col = idx & 31;
  const float* xr = x + (size_t)row * F_;
  float acc = 0.f;
#pragma unroll
  for (int k = 0; k < F_; k += 4) {
    float4 xv = *(const float4*)(xr + k);
    acc = fmaf(xv.x, w_s[(k + 0) * H1_ + col], acc);
    acc = fmaf(xv.y, w_s[(k + 1) * H1_ + col], acc);
    acc = fmaf(xv.z, w_s[(k + 2) * H1_ + col], acc);
    acc = fmaf(xv.w, w_s[(k + 3) * H1_ + col], acc);
  }
  xw1[idx] = acc;
}

// ---------------- kernel 3: hw2 = h1 @ W2   [B*N,32] @ [32,64] ----------------
__global__ __launch_bounds__(256) void k_hw2(const float* __restrict__ h1,
                                             const float* __restrict__ W2,
                                             float* __restrict__ hw2) {
  __shared__ float w_s[H1_ * H2_];
  for (int i = threadIdx.x; i < H1_ * H2_; i += 256) w_s[i] = W2[i];
  __syncthreads();
  int idx = blockIdx.x * 256 + threadIdx.x;     // over B*N*H2
  int row = idx >> 6, col = idx & 63;
  const float* hr = h1 + (size_t)row * H1_;
  float acc = 0.f;
#pragma unroll
  for (int k = 0; k < H1_; k += 4) {
    float4 hv = *(const float4*)(hr + k);
    acc = fmaf(hv.x, w_s[(k + 0) * H2_ + col], acc);
    acc = fmaf(hv.y, w_s[(k + 1) * H2_ + col], acc);
    acc = fmaf(hv.z, w_s[(k + 2) * H2_ + col], acc);
    acc = fmaf(hv.w, w_s[(k + 3) * H2_ + col], acc);
  }
  hw2[idx] = acc;
}

// -------- kernels 2/4: partial tiles of A @ B, K-split by KS_ --------
// Grid (N/64, B, KS). Each block: 64 rows x H cols over a 512-K segment.
// A staged ROW-MAJOR [64][32+12] (stride 44): float4 stores are bank-balanced
// (8 lanes per bank-quad = b128 floor), float4 reads are 2-way aliased (free).
// Register prefetch of the next A tile hides HBM latency under the FMA chunk.
// B (L2-resident) read from global with 16-lane broadcast.
template<int H, int CPT>
__global__ __launch_bounds__(256, 4) void k_agemm_part(const float* __restrict__ A,
                                                       const float* __restrict__ Bm,
                                                       float* __restrict__ part) {
  constexpr int BM = 64, BK = 32;
  constexpr int CG = H / CPT;               // col groups (16)
  constexpr int RPT = BM / (256 / CG);      // rows per thread (4)
  constexpr int QPT = (BM * BK / 4) / 256;  // 2 float4 loads per thread per chunk
  __shared__ float a_s[BM][BK + 12];        // stride 44 floats

  const int batch = blockIdx.y;
  const int m0 = blockIdx.x * BM;
  const int kbase = blockIdx.z * KSEG_;
  const float* Ab = A + (size_t)batch * N_ * N_ + (size_t)m0 * N_ + kbase;
  const float* Bb = Bm + ((size_t)batch * N_ + kbase) * H;
  const int tx = threadIdx.x % CG;
  const int ty = threadIdx.x / CG;
  const int r0 = ty * RPT;
  const int c0 = tx * CPT;

  int qrow[QPT], qk[QPT];
#pragma unroll
  for (int i = 0; i < QPT; ++i) {
    int q = threadIdx.x + i * 256;
    qrow[i] = q >> 3;            // 8 quads per row (BK/4)
    qk[i] = (q & 7) * 4;
  }
  float4 pref[QPT];
#pragma unroll
  for (int i = 0; i < QPT; ++i)
    pref[i] = *(const float4*)(Ab + (size_t)qrow[i] * N_ + qk[i]);

  float acc[RPT][CPT] = {};

  for (int kk = 0; kk < KSEG_; kk += BK) {
    if (kk) __syncthreads();            // everyone done reading previous tile
#pragma unroll
    for (int i = 0; i < QPT; ++i)       // direct float4 store, row-major
      *(float4*)&a_s[qrow[i]][qk[i]] = pref[i];
    __syncthreads();
    if (kk + BK < KSEG_) {              // prefetch next tile (hidden by compute)
#pragma unroll
      for (int i = 0; i < QPT; ++i)
        pref[i] = *(const float4*)(Ab + (size_t)qrow[i] * N_ + (kk + BK) + qk[i]);
    }
#pragma unroll
    for (int k4 = 0; k4 < BK; k4 += 4) {
      float a4[RPT][4];
#pragma unroll
      for (int m = 0; m < RPT; ++m)
        *(float4*)a4[m] = *(const float4*)&a_s[r0 + m][k4];
      const float* Bk = Bb + (size_t)(kk + k4) * H + c0;
      float bv[4][CPT];
#pragma unroll
      for (int t = 0; t < 4; ++t) {
        if constexpr (CPT == 4) *(float4*)bv[t] = *(const float4*)(Bk + t * H);
        else                    *(float2*)bv[t] = *(const float2*)(Bk + t * H);
      }
#pragma unroll
      for (int m = 0; m < RPT; ++m)
#pragma unroll
        for (int t = 0; t < 4; ++t)
#pragma unroll
          for (int c = 0; c < CPT; ++c)
            acc[m][c] = fmaf(a4[m][t], bv[t][c], acc[m][c]);
    }
  }
#pragma unroll
  for (int m = 0; m < RPT; ++m) {
    float* pp = part + (((size_t)(blockIdx.z * B_ + batch) * N_ + (m0 + r0 + m)) * H + c0);
    if constexpr (CPT == 4) *(float4*)pp = *(float4*)acc[m];
    else                    *(float2*)pp = *(float2*)acc[m];
  }
}

// -------- reduce KS partials + bias + relu (vectorized float4) --------
template<int H>
__global__ __launch_bounds__(256) void k_part_reduce(const float* __restrict__ part,
                                                     const float* __restrict__ bias,
                                                     float* __restrict__ out) {
  constexpr int TOT4 = B_ * N_ * H / 4;
  int idx = blockIdx.x * 256 + threadIdx.x;
  const float4* p4 = (const float4*)part;
  float4 s  = p4[idx];
  float4 t1 = p4[idx + TOT4];
  float4 t2 = p4[idx + 2 * TOT4];
  float4 t3 = p4[idx + 3 * TOT4];
  float4 bv = ((const float4*)bias)[idx % (H / 4)];
  float4 o;
  o.x = fmaxf(s.x + t1.x + t2.x + t3.x + bv.x, 0.f);
  o.y = fmaxf(s.y + t1.y + t2.y + t3.y + bv.y, 0.f);
  o.z = fmaxf(s.z + t1.z + t2.z + t3.z + bv.z, 0.f);
  o.w = fmaxf(s.w + t1.w + t2.w + t3.w + bv.w, 0.f);
  ((float4*)out)[idx] = o;
}

// -------- kernel 5a: K-split partials of flat(h2) @ Wd ; Wd streamed once --------
__global__ __launch_bounds__(256) void k_dense_part(const float* __restrict__ h2,
                                                    const float* __restrict__ Wd,
                                                    float* __restrict__ part) {
  constexpr int KC = 512;                  // K rows per block; grid = 131072/512 = 256
  __shared__ float hs[B_][KC];
  const int kc0 = blockIdx.x * KC;
#pragma unroll
  for (int i = 0; i < 4; ++i) {            // stage 8 x 512 floats, coalesced
    int q = threadIdx.x + i * 256;
    int b = q >> 7;
    int kq = (q & 127) * 4;
    *(float4*)&hs[b][kq] = *(const float4*)(h2 + (size_t)b * (N_ * H2_) + kc0 + kq);
  }
  __syncthreads();
  const int d0 = (threadIdx.x & 31) * 4;   // 4 output cols per thread
  const int b  = threadIdx.x >> 5;         // 1 batch per thread
  float a0 = 0.f, a1 = 0.f, a2 = 0.f, a3 = 0.f;
  const float* wp = Wd + (size_t)kc0 * D1_ + d0;
#pragma unroll 4
  for (int k = 0; k < KC; ++k) {
    float4 w = *(const float4*)(wp + (size_t)k * D1_);
    float h = hs[b][k];
    a0 = fmaf(h, w.x, a0);
    a1 = fmaf(h, w.y, a1);
    a2 = fmaf(h, w.z, a2);
    a3 = fmaf(h, w.w, a3);
  }
  float* pp = part + ((size_t)blockIdx.x * B_ + b) * D1_ + d0;
  *(float4*)pp = make_float4(a0, a1, a2, a3);
}

// -------- kernel 5b: reduce partials + bias + relu -> hd [8,128] --------
__global__ __launch_bounds__(256) void k_dense_reduce(const float* __restrict__ part,
                                                      const float* __restrict__ bd,
                                                      float* __restrict__ hd) {
  int idx = blockIdx.x * 256 + threadIdx.x;   // 0..1023 = b*128+d
  float s = 0.f;
  for (int i = 0; i < 256; ++i) s += part[(size_t)i * (B_ * D1_) + idx];
  hd[idx] = fmaxf(s + bd[idx & (D1_ - 1)], 0.f);
}

// -------- kernel 6: out[b] = sigmoid(hd[b,:] . Wo + bo) --------
__global__ __launch_bounds__(512) void k_final(const float* __restrict__ hd,
                                               const float* __restrict__ Wo,
                                               const float* __restrict__ bo,
                                               float* __restrict__ out) {
  int w = threadIdx.x >> 6;   // wave id = batch
  int l = threadIdx.x & 63;
  float v = hd[w * D1_ + l] * Wo[l] + hd[w * D1_ + 64 + l] * Wo[64 + l];
#pragma unroll
  for (int off = 32; off; off >>= 1) v += __shfl_down(v, off, 64);
  if (l == 0) out[w] = 1.f / (1.f + expf(-(v + bo[0])));
}

extern "C" void kernel_launch(void* const* d_in, const int* in_sizes, int n_in,
                              void* d_out, int out_size, void* d_ws, size_t ws_size,
                              hipStream_t stream) {
  const float* x  = (const float*)d_in[0];
  const float* a  = (const float*)d_in[1];
  const float* W1 = (const float*)d_in[2];
  const float* b1 = (const float*)d_in[3];
  const float* W2 = (const float*)d_in[4];
  const float* b2 = (const float*)d_in[5];
  const float* Wd = (const float*)d_in[6];
  const float* bd = (const float*)d_in[7];
  const float* Wo = (const float*)d_in[8];
  const float* bo = (const float*)d_in[9];
  float* out = (float*)d_out;

  // workspace layout (floats), with lifetime-based aliasing; total 25.2 MB:
  //  [0, 4194304)          P: agemm partials (pass1 uses 1st half) ... later dpart/hd
  //  [4194304, 4718592)    xw1 (2 MB)        ... later h2 (aliases xw1+h1, both dead)
  //  [4718592, 5242880)    h1  (2 MB)
  //  [5242880, 6291456)    hw2 (4 MB)
  float* ws    = (float*)d_ws;
  float* P     = ws;
  float* xw1   = ws + 4194304;
  float* h1    = ws + 4718592;
  float* hw2   = ws + 5242880;
  float* h2    = ws + 4194304;   // aliases xw1/h1 (dead by then)
  float* dpart = ws;             // aliases P (dead by then)
  float* hd    = ws + 262144;    // after dpart, still inside old P region

  k_xw1<<<(B_ * N_ * H1_) / 256, 256, 0, stream>>>(x, W1, xw1);
  k_agemm_part<H1_, 2><<<dim3(N_ / 64, B_, KS_), 256, 0, stream>>>(a, xw1, P);
  k_part_reduce<H1_><<<(B_ * N_ * H1_ / 4) / 256, 256, 0, stream>>>(P, b1, h1);
  k_hw2<<<(B_ * N_ * H2_) / 256, 256, 0, stream>>>(h1, W2, hw2);
  k_agemm_part<H2_, 4><<<dim3(N_ / 64, B_, KS_), 256, 0, stream>>>(a, hw2, P);
  k_part_reduce<H2_><<<(B_ * N_ * H2_ / 4) / 256, 256, 0, stream>>>(P, b2, h2);
  k_dense_part<<<(N_ * H2_) / 512, 256, 0, stream>>>(h2, Wd, dpart);
  k_dense_reduce<<<4, 256, 0, stream>>>(dpart, bd, hd);
  k_final<<<1, 512, 0, stream>>>(hd, Wo, bo, out);
}

// Round 5
// 193.539 us; speedup vs baseline: 1.5146x; 1.4267x over previous
//
#include <hip/hip_runtime.h>
#include <math.h>

#define B_  8
#define N_  2048
#define F_  128
#define H1_ 32
#define H2_ 64
#define D1_ 128
#define KS_ 4            // K-split factor for the A-GEMMs
#define KSEG_ (N_ / KS_) // 512 K per block

typedef unsigned short u16;
typedef unsigned int   u32;
typedef __attribute__((ext_vector_type(8))) short short8;  // 8 bf16 (4 VGPRs)
typedef __attribute__((ext_vector_type(4))) float f32x4;

// ---------------- kernel 1: xw1 = x @ W1   [B*N,128] @ [128,32] ----------------
__global__ __launch_bounds__(256) void k_xw1(const float* __restrict__ x,
                                             const float* __restrict__ W1,
                                             float* __restrict__ xw1) {
  __shared__ float w_s[F_ * H1_];
  for (int i = threadIdx.x; i < F_ * H1_; i += 256) w_s[i] = W1[i];
  __syncthreads();
  int idx = blockIdx.x * 256 + threadIdx.x;     // over B*N*H1
  int row = idx >> 5, col = idx & 31;
  const float* xr = x + (size_t)row * F_;
  float acc = 0.f;
#pragma unroll
  for (int k = 0; k < F_; k += 4) {
    float4 xv = *(const float4*)(xr + k);
    acc = fmaf(xv.x, w_s[(k + 0) * H1_ + col], acc);
    acc = fmaf(xv.y, w_s[(k + 1) * H1_ + col], acc);
    acc = fmaf(xv.z, w_s[(k + 2) * H1_ + col], acc);
    acc = fmaf(xv.w, w_s[(k + 3) * H1_ + col], acc);
  }
  xw1[idx] = acc;
}

// ---------------- kernel: hw2 = h1 @ W2   [B*N,32] @ [32,64] ----------------
__global__ __launch_bounds__(256) void k_hw2(const float* __restrict__ h1,
                                             const float* __restrict__ W2,
                                             float* __restrict__ hw2) {
  __shared__ float w_s[H1_ * H2_];
  for (int i = threadIdx.x; i < H1_ * H2_; i += 256) w_s[i] = W2[i];
  __syncthreads();
  int idx = blockIdx.x * 256 + threadIdx.x;     // over B*N*H2
  int row = idx >> 6, col = idx & 63;
  const float* hr = h1 + (size_t)row * H1_;
  float acc = 0.f;
#pragma unroll
  for (int k = 0; k < H1_; k += 4) {
    float4 hv = *(const float4*)(hr + k);
    acc = fmaf(hv.x, w_s[(k + 0) * H2_ + col], acc);
    acc = fmaf(hv.y, w_s[(k + 1) * H2_ + col], acc);
    acc = fmaf(hv.z, w_s[(k + 2) * H2_ + col], acc);
    acc = fmaf(hv.w, w_s[(k + 3) * H2_ + col], acc);
  }
  hw2[idx] = acc;
}

// ---- transpose + split-convert: in [B][N][H] fp32 -> out_hi/out_lo [B][H][N] bf16 ----
// hi = truncate-to-bf16(x); lo = truncate-to-bf16(x - hi)  (x - hi is exact in fp32)
template<int H>
__global__ __launch_bounds__(256) void k_t_cvt(const float* __restrict__ in,
                                               u16* __restrict__ out_hi,
                                               u16* __restrict__ out_lo) {
  __shared__ float s[64][H + 1];
  const int b = blockIdx.y;
  const int n0 = blockIdx.x * 64;
  const float* ip = in + ((size_t)b * N_ + n0) * H;
  constexpr int F4 = 64 * H / 4 / 256;          // float4 loads per thread
#pragma unroll
  for (int i = 0; i < F4; ++i) {
    int q = threadIdx.x + i * 256;
    int r = q / (H / 4), c4 = q % (H / 4);
    float4 v = *(const float4*)(ip + r * H + c4 * 4);
    s[r][c4 * 4 + 0] = v.x; s[r][c4 * 4 + 1] = v.y;
    s[r][c4 * 4 + 2] = v.z; s[r][c4 * 4 + 3] = v.w;
  }
  __syncthreads();
  constexpr int PASSES = H * 8 / 256;           // (H rows) x (8 threads/row of 8 n each)
#pragma unroll
  for (int p = 0; p < PASSES; ++p) {
    int q = threadIdx.x + p * 256;
    int h = q >> 3, nn = (q & 7) * 8;
    uint4 hv, lv;
    u32 hw[4], lw[4];
#pragma unroll
    for (int j = 0; j < 4; ++j) {
      float e0 = s[nn + 2 * j][h], e1 = s[nn + 2 * j + 1][h];
      u32 u0 = __float_as_uint(e0), u1 = __float_as_uint(e1);
      hw[j] = (u1 & 0xFFFF0000u) | (u0 >> 16);
      float l0 = e0 - __uint_as_float(u0 & 0xFFFF0000u);
      float l1 = e1 - __uint_as_float(u1 & 0xFFFF0000u);
      lw[j] = (__float_as_uint(l1) & 0xFFFF0000u) | (__float_as_uint(l0) >> 16);
    }
    hv.x = hw[0]; hv.y = hw[1]; hv.z = hw[2]; hv.w = hw[3];
    lv.x = lw[0]; lv.y = lw[1]; lv.z = lw[2]; lv.w = lw[3];
    size_t o = ((size_t)b * H + h) * N_ + n0 + nn;
    *(uint4*)(out_hi + o) = hv;
    *(uint4*)(out_lo + o) = lv;
  }
}

// ---- split fp32->bf16 hi/lo of 8 floats held in two float4 ----
__device__ __forceinline__ void cvt_split(const float4 a, const float4 b,
                                          short8& hi, short8& lo) {
  union { short8 s; uint4 u; } Hh, Ll;
  float e[8] = {a.x, a.y, a.z, a.w, b.x, b.y, b.z, b.w};
  u32 hw[4], lw[4];
#pragma unroll
  for (int j = 0; j < 4; ++j) {
    u32 u0 = __float_as_uint(e[2 * j]), u1 = __float_as_uint(e[2 * j + 1]);
    hw[j] = (u1 & 0xFFFF0000u) | (u0 >> 16);
    float l0 = e[2 * j] - __uint_as_float(u0 & 0xFFFF0000u);
    float l1 = e[2 * j + 1] - __uint_as_float(u1 & 0xFFFF0000u);
    lw[j] = (__float_as_uint(l1) & 0xFFFF0000u) | (__float_as_uint(l0) >> 16);
  }
  Hh.u.x = hw[0]; Hh.u.y = hw[1]; Hh.u.z = hw[2]; Hh.u.w = hw[3];
  Ll.u.x = lw[0]; Ll.u.y = lw[1]; Ll.u.z = lw[2]; Ll.u.w = lw[3];
  hi = Hh.s; lo = Ll.s;
}

// -------- MFMA A-GEMM partials: P[z] += A(fp32->split bf16) @ Bt(pre-split bf16) --------
// Wave = 16 rows x H cols. A-frag: lane holds A[lane&15][(lane>>4)*8 + i] (8 fp32 direct
// from global, L3-resident; converted in-reg). B-frag: lane holds B[(lane>>4)*8+i][lane&15]
// = Bt[col][k] -> contiguous 16B. 3 MFMAs (hh, hl, lh) per n-tile per 32-K chunk.
template<int H>
__global__ __launch_bounds__(256, 4) void k_agemm_mfma(const float* __restrict__ A,
                                                       const u16* __restrict__ Bth,
                                                       const u16* __restrict__ Btl,
                                                       float* __restrict__ P) {
  constexpr int NT = H / 16;
  const int batch = blockIdx.y;
  const int z = blockIdx.z;
  const int lane = threadIdx.x & 63;
  const int wave = threadIdx.x >> 6;
  const int arow = blockIdx.x * 64 + wave * 16 + (lane & 15);
  const int kfrag = (lane >> 4) * 8;

  const float* Ap = A + (size_t)batch * N_ * N_ + (size_t)arow * N_ + z * KSEG_ + kfrag;
  const u16* bh0 = Bth + ((size_t)batch * H + (lane & 15)) * N_ + z * KSEG_ + kfrag;
  const u16* bl0 = Btl + ((size_t)batch * H + (lane & 15)) * N_ + z * KSEG_ + kfrag;

  f32x4 acc[NT];
#pragma unroll
  for (int c = 0; c < NT; ++c) acc[c] = (f32x4){0.f, 0.f, 0.f, 0.f};

  float4 pa0 = *(const float4*)(Ap);          // prefetch chunk 0
  float4 pa1 = *(const float4*)(Ap + 4);

  for (int kk = 0; kk < KSEG_; kk += 32) {
    float4 ca0 = pa0, ca1 = pa1;
    if (kk + 32 < KSEG_) {                    // prefetch next A chunk
      pa0 = *(const float4*)(Ap + kk + 32);
      pa1 = *(const float4*)(Ap + kk + 36);
    }
    union { short8 s; uint4 u; } bh[NT], bl[NT];
#pragma unroll
    for (int c = 0; c < NT; ++c) {            // B frags: L2-resident 16B loads
      bh[c].u = *(const uint4*)(bh0 + (size_t)c * 16 * N_ + kk);
      bl[c].u = *(const uint4*)(bl0 + (size_t)c * 16 * N_ + kk);
    }
    short8 ahi, alo;
    cvt_split(ca0, ca1, ahi, alo);
#pragma unroll
    for (int c = 0; c < NT; ++c) {
      acc[c] = __builtin_amdgcn_mfma_f32_16x16x32_bf16(ahi, bh[c].s, acc[c], 0, 0, 0);
      acc[c] = __builtin_amdgcn_mfma_f32_16x16x32_bf16(ahi, bl[c].s, acc[c], 0, 0, 0);
      acc[c] = __builtin_amdgcn_mfma_f32_16x16x32_bf16(alo, bh[c].s, acc[c], 0, 0, 0);
    }
  }
  // C/D layout (m89): col = lane&15, row = (lane>>4)*4 + j
  const int orow = blockIdx.x * 64 + wave * 16 + ((lane >> 4) << 2);
  float* pp = P + ((size_t)(z * B_ + batch) * N_ + orow) * H + (lane & 15);
#pragma unroll
  for (int c = 0; c < NT; ++c)
#pragma unroll
    for (int j = 0; j < 4; ++j)
      pp[(size_t)j * H + c * 16] = acc[c][j];
}

// -------- reduce KS partials + bias + relu (vectorized float4) --------
template<int H>
__global__ __launch_bounds__(256) void k_part_reduce(const float* __restrict__ part,
                                                     const float* __restrict__ bias,
                                                     float* __restrict__ out) {
  constexpr int TOT4 = B_ * N_ * H / 4;
  int idx = blockIdx.x * 256 + threadIdx.x;
  const float4* p4 = (const float4*)part;
  float4 s  = p4[idx];
  float4 t1 = p4[idx + TOT4];
  float4 t2 = p4[idx + 2 * TOT4];
  float4 t3 = p4[idx + 3 * TOT4];
  float4 bv = ((const float4*)bias)[idx % (H / 4)];
  float4 o;
  o.x = fmaxf(s.x + t1.x + t2.x + t3.x + bv.x, 0.f);
  o.y = fmaxf(s.y + t1.y + t2.y + t3.y + bv.y, 0.f);
  o.z = fmaxf(s.z + t1.z + t2.z + t3.z + bv.z, 0.f);
  o.w = fmaxf(s.w + t1.w + t2.w + t3.w + bv.w, 0.f);
  ((float4*)out)[idx] = o;
}

// -------- dense 5a: K-split partials of flat(h2) @ Wd; Wd streamed once --------
__global__ __launch_bounds__(512) void k_dense_part(const float* __restrict__ h2,
                                                    const float* __restrict__ Wd,
                                                    float* __restrict__ part) {
  constexpr int KC = 512;                  // K rows per block; grid = 131072/512 = 256
  __shared__ float hs[B_][KC];
  __shared__ float psum[B_][D1_];
  const int kc0 = blockIdx.x * KC;
  const int tid = threadIdx.x;
#pragma unroll
  for (int i = 0; i < 2; ++i) {            // stage 8 x 512 floats, coalesced
    int q = tid + i * 512;
    int b = q >> 7, kq = (q & 127) * 4;
    *(float4*)&hs[b][kq] = *(const float4*)(h2 + (size_t)b * (N_ * H2_) + kc0 + kq);
  }
  __syncthreads();
  const int d0 = (tid & 31) * 4;           // 4 output cols
  const int b  = (tid >> 5) & 7;           // batch
  const int ks = tid >> 8;                 // in-block k-split (0/1)
  float a0 = 0.f, a1 = 0.f, a2 = 0.f, a3 = 0.f;
  const float* wp = Wd + ((size_t)kc0 + ks * 256) * D1_ + d0;
  const float* hp = &hs[b][ks * 256];
#pragma unroll 4
  for (int k = 0; k < 256; ++k) {
    float4 w = *(const float4*)(wp + (size_t)k * D1_);
    float h = hp[k];
    a0 = fmaf(h, w.x, a0); a1 = fmaf(h, w.y, a1);
    a2 = fmaf(h, w.z, a2); a3 = fmaf(h, w.w, a3);
  }
  if (ks == 1) {
    psum[b][d0] = a0; psum[b][d0 + 1] = a1; psum[b][d0 + 2] = a2; psum[b][d0 + 3] = a3;
  }
  __syncthreads();
  if (ks == 0) {
    float* pp = part + ((size_t)blockIdx.x * B_ + b) * D1_ + d0;
    *(float4*)pp = make_float4(a0 + psum[b][d0], a1 + psum[b][d0 + 1],
                               a2 + psum[b][d0 + 2], a3 + psum[b][d0 + 3]);
  }
}

// -------- dense 5b: reduce partials + bias + relu -> hd [8,128] --------
__global__ __launch_bounds__(256) void k_dense_reduce(const float* __restrict__ part,
                                                      const float* __restrict__ bd,
                                                      float* __restrict__ hd) {
  int idx = blockIdx.x * 256 + threadIdx.x;   // 0..1023 = b*128+d
  float s = 0.f;
  for (int i = 0; i < 256; ++i) s += part[(size_t)i * (B_ * D1_) + idx];
  hd[idx] = fmaxf(s + bd[idx & (D1_ - 1)], 0.f);
}

// -------- kernel 6: out[b] = sigmoid(hd[b,:] . Wo + bo) --------
__global__ __launch_bounds__(512) void k_final(const float* __restrict__ hd,
                                               const float* __restrict__ Wo,
                                               const float* __restrict__ bo,
                                               float* __restrict__ out) {
  int w = threadIdx.x >> 6;   // wave id = batch
  int l = threadIdx.x & 63;
  float v = hd[w * D1_ + l] * Wo[l] + hd[w * D1_ + 64 + l] * Wo[64 + l];
#pragma unroll
  for (int off = 32; off; off >>= 1) v += __shfl_down(v, off, 64);
  if (l == 0) out[w] = 1.f / (1.f + expf(-(v + bo[0])));
}

extern "C" void kernel_launch(void* const* d_in, const int* in_sizes, int n_in,
                              void* d_out, int out_size, void* d_ws, size_t ws_size,
                              hipStream_t stream) {
  const float* x  = (const float*)d_in[0];
  const float* a  = (const float*)d_in[1];
  const float* W1 = (const float*)d_in[2];
  const float* b1 = (const float*)d_in[3];
  const float* W2 = (const float*)d_in[4];
  const float* b2 = (const float*)d_in[5];
  const float* Wd = (const float*)d_in[6];
  const float* bd = (const float*)d_in[7];
  const float* Wo = (const float*)d_in[8];
  const float* bo = (const float*)d_in[9];
  float* out = (float*)d_out;

  // workspace (floats), lifetime-aliased; total 6,291,456 floats = 25.2 MB:
  //  [0, 4194304)          P (agemm partials)    | hw2 (before agemm2) | dpart+hd (after)
  //  [4194304, 4718592)    xw1                   | h2 [4194304,5242880) later
  //  [4718592, 5242880)    h1
  //  [5242880, 6291456)    Bt1 hi/lo (pass1)     | Bt2 hi/lo (pass2)
  float* ws   = (float*)d_ws;
  float* P    = ws;
  float* hw2  = ws;                        // alias P (P pass-1 dead by then)
  float* xw1  = ws + 4194304;
  float* h1   = ws + 4718592;
  float* h2   = ws + 4194304;              // alias xw1+h1 (both dead)
  u16*   Bt1h = (u16*)(ws + 5242880);
  u16*   Bt1l = (u16*)(ws + 5505024);
  u16*   Bt2h = (u16*)(ws + 5242880);      // alias Bt1 (dead)
  u16*   Bt2l = (u16*)(ws + 5767168);
  float* dpart = ws;                       // alias P (dead)
  float* hd   = ws + 262144;

  k_xw1<<<(B_ * N_ * H1_) / 256, 256, 0, stream>>>(x, W1, xw1);
  k_t_cvt<H1_><<<dim3(N_ / 64, B_), 256, 0, stream>>>(xw1, Bt1h, Bt1l);
  k_agemm_mfma<H1_><<<dim3(N_ / 64, B_, KS_), 256, 0, stream>>>(a, Bt1h, Bt1l, P);
  k_part_reduce<H1_><<<(B_ * N_ * H1_ / 4) / 256, 256, 0, stream>>>(P, b1, h1);
  k_hw2<<<(B_ * N_ * H2_) / 256, 256, 0, stream>>>(h1, W2, hw2);
  k_t_cvt<H2_><<<dim3(N_ / 64, B_), 256, 0, stream>>>(hw2, Bt2h, Bt2l);
  k_agemm_mfma<H2_><<<dim3(N_ / 64, B_, KS_), 256, 0, stream>>>(a, Bt2h, Bt2l, P);
  k_part_reduce<H2_><<<(B_ * N_ * H2_ / 4) / 256, 256, 0, stream>>>(P, b2, h2);
  k_dense_part<<<(N_ * H2_) / 512, 512, 0, stream>>>(h2, Wd, dpart);
  k_dense_reduce<<<4, 256, 0, stream>>>(dpart, bd, hd);
  k_final<<<1, 512, 0, stream>>>(hd, Wo, bo, out);
}